// Round 2
// baseline (350.738 us; speedup 1.0000x reference)
//
#include <hip/hip_runtime.h>

// SqueezeExcitation: x[32,256,64,64] f32, W1[64,256], b1[64], W2[256,64], b2[256]
// y = x * hardsigmoid( relu( mean_hw(x) @ W1^T + b1 ) @ W2^T + b2 )
// conv1x1 is linear => mean-then-matvec == matvec-then-mean. Two passes over x:
//   K1: per-(b,c) spatial mean; last block per batch computes the gate in-kernel
//       (device-scope atomic + threadfence "last block" pattern).
//   K2: y = x * gate[b,c], non-temporal stores (y never re-read; keep x in L3).

#define SE_B  32
#define SE_C  256
#define SE_SQ 64
#define SE_HW 4096   // 64*64

typedef float f32x4 __attribute__((ext_vector_type(4)));

// ---------------- Kernel 1: spatial mean + fused gate -----------------------
// one block (256 threads) per (b,c). The 256th block to finish within a batch
// computes that batch's gate vector (identical math to a separate kernel).
__global__ __launch_bounds__(256) void se_mean_gate_kernel(
    const float* __restrict__ x,
    const float* __restrict__ W1, const float* __restrict__ b1,
    const float* __restrict__ W2, const float* __restrict__ b2,
    float* __restrict__ m, float* __restrict__ gate, int* __restrict__ cnt) {
    const int bc = blockIdx.x;       // [0, B*C)
    const int b  = bc >> 8;
    const int t  = threadIdx.x;

    const f32x4* xv = reinterpret_cast<const f32x4*>(x) + (size_t)bc * (SE_HW / 4);
    float s = 0.0f;
#pragma unroll
    for (int k = 0; k < 4; ++k) {
        f32x4 v = xv[t + 256 * k];
        s += (v.x + v.y) + (v.z + v.w);
    }
#pragma unroll
    for (int off = 32; off > 0; off >>= 1) s += __shfl_down(s, off);

    __shared__ float wsum[4];
    __shared__ int lastFlag;
    if ((t & 63) == 0) wsum[t >> 6] = s;
    __syncthreads();

    if (t == 0) {
        m[bc] = (wsum[0] + wsum[1] + wsum[2] + wsum[3]) * (1.0f / SE_HW);
        __threadfence();                         // publish m[bc] device-wide
        int old = atomicAdd(&cnt[b], 1);         // device-scope by default
        lastFlag = (old == SE_C - 1);
    }
    __syncthreads();
    if (!lastFlag) return;

    // last block for batch b: all 256 means of this batch are published
    __threadfence();                             // acquire: see other blocks' m[]
    __shared__ float sm[SE_C];
    __shared__ float ss[SE_SQ];
    sm[t] = m[b * SE_C + t];
    __syncthreads();

    if (t < SE_SQ) {
        float acc = b1[t];
        const float* w = W1 + t * SE_C;
#pragma unroll 8
        for (int c = 0; c < SE_C; ++c) acc = fmaf(w[c], sm[c], acc);
        ss[t] = fmaxf(acc, 0.0f);
    }
    __syncthreads();

    float acc = b2[t];
    const float* w = W2 + t * SE_SQ;
#pragma unroll 8
    for (int o = 0; o < SE_SQ; ++o) acc = fmaf(w[o], ss[o], acc);
    float g = acc * (1.0f / 6.0f) + 0.5f;
    gate[b * SE_C + t] = fminf(fmaxf(g, 0.0f), 1.0f);
}

// ---------------- Kernel 2: y = x * gate[b,c] -------------------------------
// one block per (b,c): gate is one scalar (SGPR) load; nt stores for y.
__global__ __launch_bounds__(256) void se_scale_kernel(
    const float* __restrict__ x, const float* __restrict__ gate,
    float* __restrict__ y) {
    const int bc = blockIdx.x;
    const int t  = threadIdx.x;
    const float g = gate[bc];                    // uniform -> scalar load
    const f32x4* xv = reinterpret_cast<const f32x4*>(x) + (size_t)bc * (SE_HW / 4);
    f32x4*       yv = reinterpret_cast<f32x4*>(y)       + (size_t)bc * (SE_HW / 4);
#pragma unroll
    for (int k = 0; k < 4; ++k) {
        f32x4 v = xv[t + 256 * k];
        v *= g;
        __builtin_nontemporal_store(v, &yv[t + 256 * k]);
    }
}

extern "C" void kernel_launch(void* const* d_in, const int* in_sizes, int n_in,
                              void* d_out, int out_size, void* d_ws, size_t ws_size,
                              hipStream_t stream) {
    const float* x  = (const float*)d_in[0];
    const float* W1 = (const float*)d_in[1];
    const float* b1 = (const float*)d_in[2];
    const float* W2 = (const float*)d_in[3];
    const float* b2 = (const float*)d_in[4];
    float* y = (float*)d_out;

    float* m    = (float*)d_ws;                  // B*C floats
    float* gate = m + SE_B * SE_C;               // B*C floats
    int*   cnt  = (int*)(gate + SE_B * SE_C);    // B ints

    // counters must be zero every call (ws is not re-poisoned between replays)
    hipMemsetAsync(cnt, 0, SE_B * sizeof(int), stream);

    se_mean_gate_kernel<<<SE_B * SE_C, 256, 0, stream>>>(x, W1, b1, W2, b2, m, gate, cnt);
    se_scale_kernel<<<SE_B * SE_C, 256, 0, stream>>>(x, gate, y);
}

// Round 3
// 73.393 us; speedup vs baseline: 4.7789x; 4.7789x over previous
//
#include <hip/hip_runtime.h>

// SqueezeExcitation: x[32,256,64,64] f32, W1[64,256], b1[64], W2[256,64], b2[256]
// y = x * hardsigmoid( relu( mean_hw(x) @ W1^T + b1 ) @ W2^T + b2 )
// conv1x1 is linear => mean-then-matvec == matvec-then-mean. Three kernels:
//   K1: per-(b,c) spatial mean                      (reads x, 128 MiB)
//   K2: tiny per-batch gate matvec                  (negligible)
//   K3: y = x * gate[b,c], nontemporal y stores     (reads x again, writes y)
// Round-2 lesson: NO cross-block atomics/fences — 8192 contended device-scope
// atomics on shared cachelines serialized at ~50ns each (448 us total).

#define SE_B  32
#define SE_C  256
#define SE_SQ 64
#define SE_HW 4096   // 64*64

typedef float f32x4 __attribute__((ext_vector_type(4)));

// ---------------- Kernel 1: per-(b,c) spatial mean --------------------------
// one block (256 threads) per (b,c); 4096 floats = 1024 float4
__global__ __launch_bounds__(256) void se_mean_kernel(
    const float* __restrict__ x, float* __restrict__ m) {
    const int bc = blockIdx.x;                       // [0, B*C)
    const int t  = threadIdx.x;
    const f32x4* xv = reinterpret_cast<const f32x4*>(x) + (size_t)bc * (SE_HW / 4);

    float s = 0.0f;
#pragma unroll
    for (int k = 0; k < 4; ++k) {
        f32x4 v = xv[t + 256 * k];
        s += (v.x + v.y) + (v.z + v.w);
    }
#pragma unroll
    for (int off = 32; off > 0; off >>= 1) s += __shfl_down(s, off);

    __shared__ float wsum[4];
    if ((t & 63) == 0) wsum[t >> 6] = s;
    __syncthreads();
    if (t == 0) m[bc] = (wsum[0] + wsum[1] + wsum[2] + wsum[3]) * (1.0f / SE_HW);
}

// ---------------- Kernel 2: gate = hardsigmoid(relu(m@W1^T+b1)@W2^T+b2) ----
// one block (256 threads) per batch element; tiny.
__global__ __launch_bounds__(256) void se_gate_kernel(
    const float* __restrict__ m,
    const float* __restrict__ W1, const float* __restrict__ b1,
    const float* __restrict__ W2, const float* __restrict__ b2,
    float* __restrict__ gate) {
    const int b = blockIdx.x;
    const int t = threadIdx.x;

    __shared__ float sm[SE_C];
    __shared__ float ss[SE_SQ];

    sm[t] = m[b * SE_C + t];
    __syncthreads();

    if (t < SE_SQ) {
        float acc = b1[t];
        const float* w = W1 + t * SE_C;
#pragma unroll 8
        for (int c = 0; c < SE_C; ++c) acc = fmaf(w[c], sm[c], acc);
        ss[t] = fmaxf(acc, 0.0f);
    }
    __syncthreads();

    float acc = b2[t];
    const float* w = W2 + t * SE_SQ;
#pragma unroll 8
    for (int o = 0; o < SE_SQ; ++o) acc = fmaf(w[o], ss[o], acc);
    float g = acc * (1.0f / 6.0f) + 0.5f;
    gate[b * SE_C + t] = fminf(fmaxf(g, 0.0f), 1.0f);
}

// ---------------- Kernel 3: y = x * gate[b,c] -------------------------------
// one block per (b,c): gate is one wave-uniform (scalar) load; nt stores for y
// so y doesn't evict x from L3 (x is read again here from Infinity Cache).
__global__ __launch_bounds__(256) void se_scale_kernel(
    const float* __restrict__ x, const float* __restrict__ gate,
    float* __restrict__ y) {
    const int bc = blockIdx.x;
    const int t  = threadIdx.x;
    const float g = gate[bc];                    // uniform -> scalar load
    const f32x4* xv = reinterpret_cast<const f32x4*>(x) + (size_t)bc * (SE_HW / 4);
    f32x4*       yv = reinterpret_cast<f32x4*>(y)       + (size_t)bc * (SE_HW / 4);
#pragma unroll
    for (int k = 0; k < 4; ++k) {
        f32x4 v = xv[t + 256 * k];
        v *= g;
        __builtin_nontemporal_store(v, &yv[t + 256 * k]);
    }
}

extern "C" void kernel_launch(void* const* d_in, const int* in_sizes, int n_in,
                              void* d_out, int out_size, void* d_ws, size_t ws_size,
                              hipStream_t stream) {
    const float* x  = (const float*)d_in[0];
    const float* W1 = (const float*)d_in[1];
    const float* b1 = (const float*)d_in[2];
    const float* W2 = (const float*)d_in[3];
    const float* b2 = (const float*)d_in[4];
    float* y = (float*)d_out;

    float* m    = (float*)d_ws;            // B*C floats
    float* gate = m + SE_B * SE_C;         // B*C floats

    se_mean_kernel<<<SE_B * SE_C, 256, 0, stream>>>(x, m);
    se_gate_kernel<<<SE_B, 256, 0, stream>>>(m, W1, b1, W2, b2, gate);
    se_scale_kernel<<<SE_B * SE_C, 256, 0, stream>>>(x, gate, y);
}